// Round 3
// baseline (327.658 us; speedup 1.0000x reference)
//
#include <hip/hip_runtime.h>
#include <hip/hip_bf16.h>
#include <stdint.h>

#define N 8192
#define FIN 128
#define H 64
#define QB 16
#define MB 128
#define KSPLIT 4
#define KLEN (N / KSPLIT)       // 2048 keys per block
#define NIT2 (KLEN / MB)        // 16 iterations

typedef __attribute__((ext_vector_type(8))) short short8;
typedef __attribute__((ext_vector_type(4))) float f32x4;

#define MFMA16(a, b, c) __builtin_amdgcn_mfma_f32_16x16x32_bf16(a, b, c, 0, 0, 0)

static __device__ __forceinline__ unsigned short f2bf(float f) {
    unsigned int u = __float_as_uint(f);
    unsigned int r = (u + 0x7FFFu + ((u >> 16) & 1u)) >> 16;
    return (unsigned short)r;
}

// -------- kernel 0: W[128,64] f32 -> W^T[64,128] bf16 (both weights) --------
__global__ __launch_bounds__(256) void wprep_kernel(const float* __restrict__ W1,
                                                    const float* __restrict__ W2,
                                                    unsigned short* __restrict__ W1T,
                                                    unsigned short* __restrict__ W2T) {
    const int i = blockIdx.x * 256 + threadIdx.x;  // 8192 total
    const int h = i >> 7, f = i & 127;
    W1T[i] = f2bf(W1[f * H + h]);
    W2T[i] = f2bf(W2[f * H + h]);
}

// -------- kernel 1: MFMA projection  seq[8192,128] @ W[128,64] -> Q(=V), K bf16 --------
__global__ __launch_bounds__(256) void proj_kernel(const float* __restrict__ seq,
                                                   const unsigned short* __restrict__ W1T,
                                                   const unsigned short* __restrict__ W2T,
                                                   unsigned short* __restrict__ Qb,
                                                   unsigned short* __restrict__ Kb) {
    const int tid = threadIdx.x;
    const int w = tid >> 6, lane = tid & 63;
    const int g = lane >> 4, c = lane & 15;
    const int r0 = blockIdx.x * 64 + w * 16;

    short8 af[4];  // A-frags: row=c, k=kc*32 + g*8 + j
#pragma unroll
    for (int kc = 0; kc < 4; ++kc) {
        const float* sp = seq + (size_t)(r0 + c) * FIN + kc * 32 + g * 8;
        const f32x4 s0 = *(const f32x4*)sp;
        const f32x4 s1 = *(const f32x4*)(sp + 4);
        short8 v;
#pragma unroll
        for (int j = 0; j < 4; ++j) {
            v[j] = (short)f2bf(s0[j]);
            v[4 + j] = (short)f2bf(s1[j]);
        }
        af[kc] = v;
    }

    f32x4 qa[4] = {}, ka[4] = {};
#pragma unroll
    for (int kc = 0; kc < 4; ++kc) {
#pragma unroll
        for (int ht = 0; ht < 4; ++ht) {
            const short8 w1f = *(const short8*)(W1T + (size_t)(ht * 16 + c) * FIN + kc * 32 + g * 8);
            const short8 w2f = *(const short8*)(W2T + (size_t)(ht * 16 + c) * FIN + kc * 32 + g * 8);
            qa[ht] = MFMA16(af[kc], w1f, qa[ht]);
            ka[ht] = MFMA16(af[kc], w2f, ka[ht]);
        }
    }
#pragma unroll
    for (int ht = 0; ht < 4; ++ht)
#pragma unroll
        for (int r = 0; r < 4; ++r) {
            const int row = r0 + g * 4 + r;
            Qb[(size_t)row * H + ht * 16 + c] = f2bf(qa[ht][r]);
            Kb[(size_t)row * H + ht * 16 + c] = f2bf(ka[ht][r]);
        }
}

// -------- kernel 2: transpose Qb[8192,64] -> QT[64,8192] (bf16, = V^T) --------
__global__ __launch_bounds__(256) void tr_kernel(const unsigned short* __restrict__ Qb,
                                                 unsigned short* __restrict__ QT) {
    __shared__ unsigned short t[64][65];
    const int m0 = blockIdx.x * 64;
    const int tid = threadIdx.x;
    for (int i = tid; i < 64 * 64; i += 256) {
        const int m = i >> 6, h = i & 63;
        t[h][m] = Qb[(size_t)(m0 + m) * H + h];
    }
    __syncthreads();
    for (int i = tid; i < 64 * 64; i += 256) {
        const int h = i >> 6, m = i & 63;
        QT[(size_t)h * N + m0 + m] = t[h][m];
    }
}

// -------- kernel 3: flash attention partials, key-split for occupancy --------
// grid = 512 q-chunks * KSPLIT key-slices = 2048 blocks -> 8 blocks/CU.
// Each block: QB=16 queries x KLEN=2048 keys, 4 waves each owning a 32-key
// slice of the 128-key tile. Writes partial numerator [16][64] + denom [16].
__global__ __launch_bounds__(256, 8) void flash_kernel(const unsigned short* __restrict__ Qb,
                                                       const unsigned short* __restrict__ Kb,
                                                       const unsigned short* __restrict__ QT,
                                                       const float* __restrict__ bias,
                                                       float* __restrict__ pv,
                                                       float* __restrict__ pd) {
    // redv doubles as the per-wave P bounce buffer during the loop
    // (P needs 1280 B/wave; redv slice is 4160 B/wave; epilogue-only overlap)
    __shared__ float redv[4][QB][65];  // [..][64] holds the wave's denom

    const int tid = threadIdx.x;
    const int w = tid >> 6, lane = tid & 63;
    const int g = lane >> 4, c = lane & 15;
    const int bid = blockIdx.x;
    const int q0 = (bid >> 2) * QB;
    const int mbase = (bid & 3) * KLEN;
    const int mwoff = w * 32;

    // Q A-fragments (row=c, k=g*8+j), H=64 -> 2 frags
    short8 qf0, qf1;
    {
        const unsigned short* qrow = Qb + (size_t)(q0 + c) * H + g * 8;
        qf0 = *(const short8*)(qrow);
        qf1 = *(const short8*)(qrow + 32);
    }

    f32x4 vals[4] = {};  // PV accum; D row=q(g*4+r), col=h(ht*16+c)
    float dsum[4] = {0.f, 0.f, 0.f, 0.f};

    const float* bbase = bias + (size_t)(q0 + g * 4) * N + c;
    float bcur[8];
#pragma unroll
    for (int t = 0; t < 2; ++t)
#pragma unroll
        for (int r = 0; r < 4; ++r)
            bcur[t * 4 + r] = bbase[(size_t)r * N + mbase + mwoff + t * 16];

    unsigned short* pp = (unsigned short*)(&redv[w][0][0]);  // wave-local P buffer

    for (int it = 0; it < NIT2; ++it) {
        const int m0 = mbase + it * MB;

        // current K fragments (L2-resident stream)
        short8 kf[2][2];
#pragma unroll
        for (int t = 0; t < 2; ++t) {
            const unsigned short* kr = Kb + (size_t)(m0 + mwoff + t * 16 + c) * H + g * 8;
            kf[t][0] = *(const short8*)(kr);
            kf[t][1] = *(const short8*)(kr + 32);
        }
        // current V^T fragments
        short8 vf[4];
#pragma unroll
        for (int ht = 0; ht < 4; ++ht)
            vf[ht] = *(const short8*)(QT + (size_t)(ht * 16 + c) * N + m0 + mwoff + g * 8);

        // prefetch next iteration's bias (the HBM stream) — issued after K/V so
        // waits on kf/vf don't force the bias drain
        float bnext[8];
        if (it + 1 < NIT2) {
            const int mn = m0 + MB + mwoff;
#pragma unroll
            for (int t = 0; t < 2; ++t)
#pragma unroll
                for (int r = 0; r < 4; ++r)
                    bnext[t * 4 + r] = bbase[(size_t)r * N + mn + t * 16];
        }

        // ---- QK^T (16x32 slice), exp, weight by bias ----
        unsigned short pw[8];
#pragma unroll
        for (int t = 0; t < 2; ++t) {
            f32x4 acc = {};
            acc = MFMA16(qf0, kf[t][0], acc);
            acc = MFMA16(qf1, kf[t][1], acc);
#pragma unroll
            for (int r = 0; r < 4; ++r) {
                const float p = __expf(acc[r] * 0.125f) * bcur[t * 4 + r];
                dsum[r] += p;
                pw[t * 4 + r] = f2bf(p);
            }
        }

        // ---- P -> wave-local LDS (stride 40 ushorts, conflict-light), A-frag back ----
#pragma unroll
        for (int t = 0; t < 2; ++t)
#pragma unroll
            for (int r = 0; r < 4; ++r)
                pp[(g * 4 + r) * 40 + t * 16 + c] = pw[t * 4 + r];
        __builtin_amdgcn_wave_barrier();
        const short8 pa = *(const short8*)(pp + c * 40 + g * 8);

        // ---- PV: vals[ht] += P(16x32) @ V(32x16) ----
#pragma unroll
        for (int ht = 0; ht < 4; ++ht)
            vals[ht] = MFMA16(pa, vf[ht], vals[ht]);

        if (it + 1 < NIT2) {
#pragma unroll
            for (int i = 0; i < 8; ++i) bcur[i] = bnext[i];
        }
    }

    // ---- denom across the 16 c-lanes ----
#pragma unroll
    for (int r = 0; r < 4; ++r) {
        float v = dsum[r];
        v += __shfl_xor(v, 1);
        v += __shfl_xor(v, 2);
        v += __shfl_xor(v, 4);
        v += __shfl_xor(v, 8);
        dsum[r] = v;
    }
    __syncthreads();  // all waves done with P region before redv reuse
#pragma unroll
    for (int ht = 0; ht < 4; ++ht)
#pragma unroll
        for (int r = 0; r < 4; ++r)
            redv[w][g * 4 + r][ht * 16 + c] = vals[ht][r];
    if (c == 0) {
#pragma unroll
        for (int r = 0; r < 4; ++r) redv[w][g * 4 + r][64] = dsum[r];
    }
    __syncthreads();

    const int h = tid & 63;
    for (int qq = tid >> 6; qq < QB; qq += 4) {
        const float v = redv[0][qq][h] + redv[1][qq][h] + redv[2][qq][h] + redv[3][qq][h];
        pv[((size_t)bid * QB + qq) * H + h] = v;
        if (h == 0) {
            const float d = redv[0][qq][64] + redv[1][qq][64] + redv[2][qq][64] + redv[3][qq][64];
            pd[(size_t)bid * QB + qq] = d;
        }
    }
}

// -------- kernel 4: combine key-split partials, divide, ELU --------
__global__ __launch_bounds__(256) void reduce_kernel(const float* __restrict__ pv,
                                                     const float* __restrict__ pd,
                                                     float* __restrict__ out) {
    const int i = blockIdx.x * 256 + threadIdx.x;  // 8192*64
    const int q = i >> 6, h = i & 63;
    const int qc = q >> 4, qi = q & 15;
    float v = 0.f, d = 0.f;
#pragma unroll
    for (int ks = 0; ks < KSPLIT; ++ks) {
        const size_t row = ((size_t)(qc * KSPLIT + ks) * QB + qi);
        v += pv[row * H + h];
        d += pd[row];
    }
    const float x = v / (d + 1e-19f);
    out[i] = x > 0.f ? x : expm1f(x);
}

extern "C" void kernel_launch(void* const* d_in, const int* in_sizes, int n_in,
                              void* d_out, int out_size, void* d_ws, size_t ws_size,
                              hipStream_t stream) {
    const float* seq  = (const float*)d_in[0];
    const float* bias = (const float*)d_in[1];
    const float* W1   = (const float*)d_in[2];
    const float* W2   = (const float*)d_in[3];
    // d_in[4] = bias_zero (all zeros) -- folded out
    float* out = (float*)d_out;

    unsigned short* Qb  = (unsigned short*)d_ws;   // 1 MB (also V)
    unsigned short* Kb  = Qb + (size_t)N * H;      // 1 MB
    unsigned short* QT  = Kb + (size_t)N * H;      // 1 MB (V^T)
    unsigned short* W1T = QT + (size_t)N * H;      // 16 KB
    unsigned short* W2T = W1T + (size_t)H * FIN;   // 16 KB
    float* pv = (float*)(W2T + (size_t)H * FIN);   // 2048*16*64 f32 = 8 MB
    float* pd = pv + (size_t)(N / QB) * KSPLIT * QB * H;  // 128 KB

    wprep_kernel<<<32, 256, 0, stream>>>(W1, W2, W1T, W2T);
    proj_kernel<<<N / 64, 256, 0, stream>>>(seq, W1T, W2T, Qb, Kb);
    tr_kernel<<<N / 64, 256, 0, stream>>>(Qb, QT);
    flash_kernel<<<(N / QB) * KSPLIT, 256, 0, stream>>>(Qb, Kb, QT, bias, pv, pd);
    reduce_kernel<<<(N * H) / 256, 256, 0, stream>>>(pv, pd, out);
}

// Round 4
// 104.587 us; speedup vs baseline: 3.1329x; 3.1329x over previous
//
#include <hip/hip_runtime.h>
#include <hip/hip_bf16.h>
#include <stdint.h>

#define N 8192
#define FIN 128
#define H 64
#define QB2 32                   // query rows per block
#define MB2 64                   // keys per iteration
#define KSPLIT 4
#define KLEN (N / KSPLIT)        // 2048 keys per block
#define NIT3 (KLEN / MB2)        // 32 iterations
#define STAGE_BYTES 24576        // K 8KB + V 8KB + bias 8KB

typedef __attribute__((ext_vector_type(8))) short short8;
typedef __attribute__((ext_vector_type(4))) float f32x4;

#define MFMA16(a, b, c) __builtin_amdgcn_mfma_f32_16x16x32_bf16(a, b, c, 0, 0, 0)

typedef __attribute__((address_space(1))) const void* gas_p;
typedef __attribute__((address_space(3))) void* las_p;

static __device__ __forceinline__ void load_lds16(const void* g, void* l) {
    // dest must be WAVE-UNIFORM base; HW writes lane i at base + i*16.
    __builtin_amdgcn_global_load_lds((gas_p)g, (las_p)l, 16, 0, 0);
}

static __device__ __forceinline__ unsigned short f2bf(float f) {
    unsigned int u = __float_as_uint(f);
    unsigned int r = (u + 0x7FFFu + ((u >> 16) & 1u)) >> 16;
    return (unsigned short)r;
}

// -------- kernel 0: W[128,64] f32 -> W^T[64,128] bf16 --------
__global__ __launch_bounds__(256) void wprep_kernel(const float* __restrict__ W1,
                                                    const float* __restrict__ W2,
                                                    unsigned short* __restrict__ W1T,
                                                    unsigned short* __restrict__ W2T) {
    const int i = blockIdx.x * 256 + threadIdx.x;
    const int h = i >> 7, f = i & 127;
    W1T[i] = f2bf(W1[f * H + h]);
    W2T[i] = f2bf(W2[f * H + h]);
}

// -------- kernel 1: MFMA projection seq @ W -> Q(=V), K in bf16 --------
__global__ __launch_bounds__(256) void proj_kernel(const float* __restrict__ seq,
                                                   const unsigned short* __restrict__ W1T,
                                                   const unsigned short* __restrict__ W2T,
                                                   unsigned short* __restrict__ Qb,
                                                   unsigned short* __restrict__ Kb) {
    const int tid = threadIdx.x;
    const int w = tid >> 6, lane = tid & 63;
    const int g = lane >> 4, c = lane & 15;
    const int r0 = blockIdx.x * 64 + w * 16;

    short8 af[4];
#pragma unroll
    for (int kc = 0; kc < 4; ++kc) {
        const float* sp = seq + (size_t)(r0 + c) * FIN + kc * 32 + g * 8;
        const f32x4 s0 = *(const f32x4*)sp;
        const f32x4 s1 = *(const f32x4*)(sp + 4);
        short8 v;
#pragma unroll
        for (int j = 0; j < 4; ++j) {
            v[j] = (short)f2bf(s0[j]);
            v[4 + j] = (short)f2bf(s1[j]);
        }
        af[kc] = v;
    }

    f32x4 qa[4] = {}, ka[4] = {};
#pragma unroll
    for (int kc = 0; kc < 4; ++kc) {
#pragma unroll
        for (int ht = 0; ht < 4; ++ht) {
            const short8 w1f = *(const short8*)(W1T + (size_t)(ht * 16 + c) * FIN + kc * 32 + g * 8);
            const short8 w2f = *(const short8*)(W2T + (size_t)(ht * 16 + c) * FIN + kc * 32 + g * 8);
            qa[ht] = MFMA16(af[kc], w1f, qa[ht]);
            ka[ht] = MFMA16(af[kc], w2f, ka[ht]);
        }
    }
#pragma unroll
    for (int ht = 0; ht < 4; ++ht)
#pragma unroll
        for (int r = 0; r < 4; ++r) {
            const int row = r0 + g * 4 + r;
            Qb[(size_t)row * H + ht * 16 + c] = f2bf(qa[ht][r]);
            Kb[(size_t)row * H + ht * 16 + c] = f2bf(ka[ht][r]);
        }
}

// -------- kernel 2: transpose Qb -> QT[64][8192] (= V^T) --------
__global__ __launch_bounds__(256) void tr_kernel(const unsigned short* __restrict__ Qb,
                                                 unsigned short* __restrict__ QT) {
    __shared__ unsigned short t[64][65];
    const int m0 = blockIdx.x * 64;
    const int tid = threadIdx.x;
    for (int i = tid; i < 64 * 64; i += 256) {
        const int m = i >> 6, h = i & 63;
        t[h][m] = Qb[(size_t)(m0 + m) * H + h];
    }
    __syncthreads();
    for (int i = tid; i < 64 * 64; i += 256) {
        const int h = i >> 6, m = i & 63;
        QT[(size_t)h * N + m0 + m] = t[h][m];
    }
}

// -------- kernel 3: flash partials, double-buffered LDS staging --------
// 1024 blocks (256 q-chunks x KSPLIT). 4 waves = 2(wq) x 2(wk):
// wave owns 16 q-rows x 32-key slice of the 32x64 tile.
// ALL streams (K, V^T, bias) staged via global_load_lds, XOR-swizzled.
__global__ __launch_bounds__(256, 3) void flash_kernel(const unsigned short* __restrict__ Qb,
                                                       const unsigned short* __restrict__ Kb,
                                                       const unsigned short* __restrict__ QT,
                                                       const float* __restrict__ bias,
                                                       float* __restrict__ pv,
                                                       float* __restrict__ pd) {
    __shared__ char smem[2 * STAGE_BYTES + 4 * 16 * 36 * 2];  // 53760 B -> 3 blocks/CU

    const int tid = threadIdx.x;
    const int w = tid >> 6, lane = tid & 63;
    const int g = lane >> 4, c = lane & 15;
    const int wq = w >> 1, wk = w & 1;
    const int bid = blockIdx.x;
    const int q0 = (bid >> 2) * QB2;
    const int mbase = (bid & 3) * KLEN;

    unsigned short* Pw = (unsigned short*)(smem + 2 * STAGE_BYTES) + w * (16 * 36);

    // Q A-fragments for this wave's 16 rows (row=c, k=g*8+j)
    short8 qf0, qf1;
    {
        const unsigned short* qrow = Qb + (size_t)(q0 + wq * 16 + c) * H + g * 8;
        qf0 = *(const short8*)(qrow);
        qf1 = *(const short8*)(qrow + 32);
    }

    f32x4 vals[4] = {};
    float dsum[4] = {0.f, 0.f, 0.f, 0.f};

    // ---- stage one 32x64 tile (K + V^T + bias) into sbase; it's tile at key m0 ----
    // wave w stages segments [w*2, w*2+2) of each 8KB stream (seg = 1024B = 64 lanes x 16B)
    auto stage = [&](char* sbase, int m0) {
#pragma unroll
        for (int s2 = 0; s2 < 2; ++s2) {
            const int s = w * 2 + s2;          // 0..7
            {   // K: [64 m][64 h] bf16, swz byte ^= (m&7)<<4
                const int m = s * 8 + (lane >> 3);
                const int srcb = ((lane & 7) * 16) ^ ((m & 7) << 4);
                load_lds16((const char*)Kb + (size_t)(mbase + m0 + m) * 128 + srcb,
                           sbase + s * 1024);
            }
            {   // V^T: [64 h][64 m] bf16, swz byte ^= (h&7)<<4
                const int h = s * 8 + (lane >> 3);
                const int srcb = ((lane & 7) * 16) ^ ((h & 7) << 4);
                load_lds16((const char*)QT + (size_t)h * (N * 2) + (size_t)(mbase + m0) * 2 + srcb,
                           sbase + 8192 + s * 1024);
            }
            {   // bias: [32 q][64 m] f32, swz float-col ^= (q&7)<<2
                const int q = s * 4 + (lane >> 4);
                const int sj = ((lane & 15) * 4) ^ ((q & 7) << 2);
                load_lds16((const char*)bias + ((size_t)(q0 + q) * N + mbase + m0 + sj) * 4,
                           sbase + 16384 + s * 1024);
            }
        }
    };

    char* sbuf0 = smem;
    char* sbuf1 = smem + STAGE_BYTES;
    stage(sbuf0, 0);
    __syncthreads();

    int cur = 0;
    for (int it = 0; it < NIT3; ++it) {
        char* sb = cur ? sbuf1 : sbuf0;
        if (it + 1 < NIT3) stage(cur ? sbuf0 : sbuf1, (it + 1) * MB2);

        const char* kb = sb;
        const char* vb = sb + 8192;
        const float* bb = (const float*)(sb + 16384);

        // bias for this wave's 16x32 sub-tile (double-XOR cancels the swizzle)
        float bcur[8];
#pragma unroll
        for (int t = 0; t < 2; ++t)
#pragma unroll
            for (int r = 0; r < 4; ++r) {
                const int q = wq * 16 + g * 4 + r;
                const int j = wk * 32 + t * 16 + c;
                bcur[t * 4 + r] = bb[q * 64 + (j ^ ((q & 7) << 2))];
            }

        // K fragments: B[k=h][col=key], key = wk*32 + t*16 + c
        short8 kf[2][2];
#pragma unroll
        for (int t = 0; t < 2; ++t) {
            const int m = wk * 32 + t * 16 + c;
            const char* kr = kb + m * 128;
            const int sw = (m & 7) << 4;
            kf[t][0] = *(const short8*)(kr + ((g * 16) ^ sw));
            kf[t][1] = *(const short8*)(kr + ((64 + g * 16) ^ sw));
        }
        // V^T fragments: B[k=key_local][col=h], h = ht*16 + c
        short8 vf[4];
#pragma unroll
        for (int ht = 0; ht < 4; ++ht) {
            const int h = ht * 16 + c;
            vf[ht] = *(const short8*)(vb + h * 128 + ((wk * 64 + g * 16) ^ ((h & 7) << 4)));
        }

        // ---- QK^T, exp, weight ----
        unsigned short pw[8];
#pragma unroll
        for (int t = 0; t < 2; ++t) {
            f32x4 acc = {};
            acc = MFMA16(qf0, kf[t][0], acc);
            acc = MFMA16(qf1, kf[t][1], acc);
#pragma unroll
            for (int r = 0; r < 4; ++r) {
                const float p = __expf(acc[r] * 0.125f) * bcur[t * 4 + r];
                dsum[r] += p;
                pw[t * 4 + r] = f2bf(p);
            }
        }

        // ---- P bounce: stride 36 ushorts (write 2-way, read spread) ----
#pragma unroll
        for (int t = 0; t < 2; ++t)
#pragma unroll
            for (int r = 0; r < 4; ++r)
                Pw[(g * 4 + r) * 36 + t * 16 + c] = pw[t * 4 + r];
        __builtin_amdgcn_wave_barrier();
        const short8 pa = *(const short8*)(Pw + c * 36 + g * 8);

        // ---- PV ----
#pragma unroll
        for (int ht = 0; ht < 4; ++ht)
            vals[ht] = MFMA16(pa, vf[ht], vals[ht]);

        __syncthreads();  // drains staging vmcnt; buffer swap safe
        cur ^= 1;
    }

    // ---- denominator across the 16 c-lanes ----
#pragma unroll
    for (int r = 0; r < 4; ++r) {
        float v = dsum[r];
        v += __shfl_xor(v, 1);
        v += __shfl_xor(v, 2);
        v += __shfl_xor(v, 4);
        v += __shfl_xor(v, 8);
        dsum[r] = v;
    }

    // ---- cross-wk combine (redv aliases the stage area; loop is done) ----
    float* rv = (float*)smem;  // [2 wk][32 q][65]
#pragma unroll
    for (int ht = 0; ht < 4; ++ht)
#pragma unroll
        for (int r = 0; r < 4; ++r)
            rv[(wk * 32 + wq * 16 + g * 4 + r) * 65 + ht * 16 + c] = vals[ht][r];
    if (c == 0) {
#pragma unroll
        for (int r = 0; r < 4; ++r)
            rv[(wk * 32 + wq * 16 + g * 4 + r) * 65 + 64] = dsum[r];
    }
    __syncthreads();

    const int h = tid & 63;
    for (int qq = tid >> 6; qq < QB2; qq += 4) {
        const float v = rv[qq * 65 + h] + rv[(32 + qq) * 65 + h];
        pv[((size_t)bid * QB2 + qq) * H + h] = v;
        if (h == 0)
            pd[(size_t)bid * QB2 + qq] = rv[qq * 65 + 64] + rv[(32 + qq) * 65 + 64];
    }
}

// -------- kernel 4: combine key-split partials, divide, ELU --------
__global__ __launch_bounds__(256) void reduce_kernel(const float* __restrict__ pv,
                                                     const float* __restrict__ pd,
                                                     float* __restrict__ out) {
    const int i = blockIdx.x * 256 + threadIdx.x;  // N*H
    const int q = i >> 6, h = i & 63;
    const int qc = q >> 5, qi = q & 31;
    float v = 0.f, d = 0.f;
#pragma unroll
    for (int ks = 0; ks < KSPLIT; ++ks) {
        const size_t row = (size_t)(qc * KSPLIT + ks) * QB2 + qi;
        v += pv[row * H + h];
        d += pd[row];
    }
    const float x = v / (d + 1e-19f);
    out[i] = x > 0.f ? x : expm1f(x);
}

extern "C" void kernel_launch(void* const* d_in, const int* in_sizes, int n_in,
                              void* d_out, int out_size, void* d_ws, size_t ws_size,
                              hipStream_t stream) {
    const float* seq  = (const float*)d_in[0];
    const float* bias = (const float*)d_in[1];
    const float* W1   = (const float*)d_in[2];
    const float* W2   = (const float*)d_in[3];
    // d_in[4] = bias_zero (zeros) -- folded out
    float* out = (float*)d_out;

    unsigned short* Qb  = (unsigned short*)d_ws;   // 1 MB (also V)
    unsigned short* Kb  = Qb + (size_t)N * H;      // 1 MB
    unsigned short* QT  = Kb + (size_t)N * H;      // 1 MB (V^T)
    unsigned short* W1T = QT + (size_t)N * H;      // 16 KB
    unsigned short* W2T = W1T + (size_t)H * FIN;   // 16 KB
    float* pv = (float*)(W2T + (size_t)H * FIN);   // 1024*32*64 f32 = 8 MB
    float* pd = pv + (size_t)(N / QB2) * KSPLIT * QB2 * H;  // 128 KB

    wprep_kernel<<<32, 256, 0, stream>>>(W1, W2, W1T, W2T);
    proj_kernel<<<N / 64, 256, 0, stream>>>(seq, W1T, W2T, Qb, Kb);
    tr_kernel<<<N / 64, 256, 0, stream>>>(Qb, QT);
    flash_kernel<<<(N / QB2) * KSPLIT, 256, 0, stream>>>(Qb, Kb, QT, bias, pv, pd);
    reduce_kernel<<<(N * H) / 256, 256, 0, stream>>>(pv, pd, out);
}

// Round 5
// 99.588 us; speedup vs baseline: 3.2902x; 1.0502x over previous
//
#include <hip/hip_runtime.h>
#include <hip/hip_bf16.h>
#include <stdint.h>

#define N 8192
#define FIN 128
#define H 64
#define QB2 32                   // query rows per block
#define MB2 64                   // keys per iteration
#define KSPLIT 4
#define KLEN (N / KSPLIT)        // 2048 keys per block
#define NIT3 (KLEN / MB2)        // 32 iterations
#define STAGE_BYTES 24576        // K 8KB + V 8KB + bias 8KB

typedef __attribute__((ext_vector_type(8))) short short8;
typedef __attribute__((ext_vector_type(4))) float f32x4;

#define MFMA16(a, b, c) __builtin_amdgcn_mfma_f32_16x16x32_bf16(a, b, c, 0, 0, 0)

typedef __attribute__((address_space(1))) const void* gas_p;
typedef __attribute__((address_space(3))) void* las_p;

static __device__ __forceinline__ void load_lds16(const void* g, void* l) {
    // dest is wave-uniform base; HW writes lane i at base + i*16.
    __builtin_amdgcn_global_load_lds((gas_p)g, (las_p)l, 16, 0, 0);
}

static __device__ __forceinline__ unsigned short f2bf(float f) {
    unsigned int u = __float_as_uint(f);
    unsigned int r = (u + 0x7FFFu + ((u >> 16) & 1u)) >> 16;
    return (unsigned short)r;
}

// -------- kernel 0: W[128,64] f32 -> W^T[64,128] bf16 --------
__global__ __launch_bounds__(256) void wprep_kernel(const float* __restrict__ W1,
                                                    const float* __restrict__ W2,
                                                    unsigned short* __restrict__ W1T,
                                                    unsigned short* __restrict__ W2T) {
    const int i = blockIdx.x * 256 + threadIdx.x;
    const int h = i >> 7, f = i & 127;
    W1T[i] = f2bf(W1[f * H + h]);
    W2T[i] = f2bf(W2[f * H + h]);
}

// -------- kernel 1: MFMA projection seq @ W -> Q(=V), K in bf16 --------
// 256 blocks x 32 rows. Waves 0-1: W1 (rows 0-15 / 16-31); waves 2-3: W2.
__global__ __launch_bounds__(256) void proj_kernel(const float* __restrict__ seq,
                                                   const unsigned short* __restrict__ W1T,
                                                   const unsigned short* __restrict__ W2T,
                                                   unsigned short* __restrict__ Qb,
                                                   unsigned short* __restrict__ Kb) {
    const int tid = threadIdx.x;
    const int w = tid >> 6, lane = tid & 63;
    const int g = lane >> 4, c = lane & 15;
    const int wq = w & 1, ww = w >> 1;
    const int r0 = blockIdx.x * 32 + wq * 16;
    const unsigned short* WT = ww ? W2T : W1T;
    unsigned short* Ob = ww ? Kb : Qb;

    short8 af[4];
#pragma unroll
    for (int kc = 0; kc < 4; ++kc) {
        const float* sp = seq + (size_t)(r0 + c) * FIN + kc * 32 + g * 8;
        const f32x4 s0 = *(const f32x4*)sp;
        const f32x4 s1 = *(const f32x4*)(sp + 4);
        short8 v;
#pragma unroll
        for (int j = 0; j < 4; ++j) {
            v[j] = (short)f2bf(s0[j]);
            v[4 + j] = (short)f2bf(s1[j]);
        }
        af[kc] = v;
    }

    f32x4 oa[4] = {};
#pragma unroll
    for (int kc = 0; kc < 4; ++kc) {
#pragma unroll
        for (int ht = 0; ht < 4; ++ht) {
            const short8 wf = *(const short8*)(WT + (size_t)(ht * 16 + c) * FIN + kc * 32 + g * 8);
            oa[ht] = MFMA16(af[kc], wf, oa[ht]);
        }
    }
#pragma unroll
    for (int ht = 0; ht < 4; ++ht)
#pragma unroll
        for (int r = 0; r < 4; ++r) {
            const int row = r0 + g * 4 + r;
            Ob[(size_t)row * H + ht * 16 + c] = f2bf(oa[ht][r]);
        }
}

// -------- kernel 2: transpose Qb -> QT[64][8192] (= V^T) --------
__global__ __launch_bounds__(256) void tr_kernel(const unsigned short* __restrict__ Qb,
                                                 unsigned short* __restrict__ QT) {
    __shared__ unsigned short t[64][65];
    const int m0 = blockIdx.x * 64;
    const int tid = threadIdx.x;
    for (int i = tid; i < 64 * 64; i += 256) {
        const int m = i >> 6, h = i & 63;
        t[h][m] = Qb[(size_t)(m0 + m) * H + h];
    }
    __syncthreads();
    for (int i = tid; i < 64 * 64; i += 256) {
        const int h = i >> 6, m = i & 63;
        QT[(size_t)h * N + m0 + m] = t[h][m];
    }
}

// -------- kernel 3: flash partials — triple-buffered, counted-vmcnt pipeline --------
// 1024 blocks (256 q-chunks x KSPLIT). 4 waves = 2(wq) x 2(wk).
// Per iter: issue stage(it+2) [6 loads/wave], compute tile it,
// s_waitcnt vmcnt(6) (drain stage it+1, keep it+2 in flight), raw s_barrier.
__global__ __launch_bounds__(256, 2) void flash_kernel(const unsigned short* __restrict__ Qb,
                                                       const unsigned short* __restrict__ Kb,
                                                       const unsigned short* __restrict__ QT,
                                                       const float* __restrict__ bias,
                                                       float* __restrict__ pv,
                                                       float* __restrict__ pd) {
    __shared__ char smem[3 * STAGE_BYTES + 4 * 16 * 36 * 2];  // 78336 B -> 2 blocks/CU

    const int tid = threadIdx.x;
    const int w = tid >> 6, lane = tid & 63;
    const int g = lane >> 4, c = lane & 15;
    const int wq = w >> 1, wk = w & 1;
    const int bid = blockIdx.x;
    const int q0 = (bid >> 2) * QB2;
    const int mbase = (bid & 3) * KLEN;

    unsigned short* Pw = (unsigned short*)(smem + 3 * STAGE_BYTES) + w * (16 * 36);

    // Q A-fragments for this wave's 16 rows (row=c, k=g*8+j)
    short8 qf0, qf1;
    {
        const unsigned short* qrow = Qb + (size_t)(q0 + wq * 16 + c) * H + g * 8;
        qf0 = *(const short8*)(qrow);
        qf1 = *(const short8*)(qrow + 32);
    }

    f32x4 vals[4] = {};
    float dsum[4] = {0.f, 0.f, 0.f, 0.f};

    // stage one 32x64 tile (K + V^T + bias); exactly 6 global_load_lds per wave
    auto stage = [&](char* sbase, int m0) {
#pragma unroll
        for (int s2 = 0; s2 < 2; ++s2) {
            const int s = w * 2 + s2;          // 0..7
            {   // K: [64 m][64 h] bf16, swz byte ^= (m&7)<<4
                const int m = s * 8 + (lane >> 3);
                const int srcb = ((lane & 7) * 16) ^ ((m & 7) << 4);
                load_lds16((const char*)Kb + (size_t)(mbase + m0 + m) * 128 + srcb,
                           sbase + s * 1024);
            }
            {   // V^T: [64 h][64 m] bf16, swz byte ^= (h&7)<<4
                const int h = s * 8 + (lane >> 3);
                const int srcb = ((lane & 7) * 16) ^ ((h & 7) << 4);
                load_lds16((const char*)QT + (size_t)h * (N * 2) + (size_t)(mbase + m0) * 2 + srcb,
                           sbase + 8192 + s * 1024);
            }
            {   // bias: [32 q][64 m] f32, swz float-col ^= (q&7)<<2
                const int q = s * 4 + (lane >> 4);
                const int sj = ((lane & 15) * 4) ^ ((q & 7) << 2);
                load_lds16((const char*)bias + ((size_t)(q0 + q) * N + mbase + m0 + sj) * 4,
                           sbase + 16384 + s * 1024);
            }
        }
    };

    char* b0 = smem;
    char* b1 = smem + STAGE_BYTES;
    char* b2 = smem + 2 * STAGE_BYTES;

    stage(b0, 0);
    stage(b1, MB2);
    asm volatile("s_waitcnt vmcnt(6)" ::: "memory");  // drain stage(0)
    __builtin_amdgcn_s_barrier();

    for (int it = 0; it < NIT3; ++it) {
        char* sb = b0;
        const bool pre = (it + 2 < NIT3);
        if (pre) stage(b2, (it + 2) * MB2);

        const char* kb = sb;
        const char* vb = sb + 8192;
        const float* bb = (const float*)(sb + 16384);

        // bias for this wave's 16x32 sub-tile (double-XOR cancels the swizzle)
        float bcur[8];
#pragma unroll
        for (int t = 0; t < 2; ++t)
#pragma unroll
            for (int r = 0; r < 4; ++r) {
                const int q = wq * 16 + g * 4 + r;
                const int j = wk * 32 + t * 16 + c;
                bcur[t * 4 + r] = bb[q * 64 + (j ^ ((q & 7) << 2))];
            }

        // K fragments: B[k=h][col=key], key = wk*32 + t*16 + c
        short8 kf[2][2];
#pragma unroll
        for (int t = 0; t < 2; ++t) {
            const int m = wk * 32 + t * 16 + c;
            const char* kr = kb + m * 128;
            const int sw = (m & 7) << 4;
            kf[t][0] = *(const short8*)(kr + ((g * 16) ^ sw));
            kf[t][1] = *(const short8*)(kr + ((64 + g * 16) ^ sw));
        }
        // V^T fragments: B[k=key_local][col=h], h = ht*16 + c
        short8 vf[4];
#pragma unroll
        for (int ht = 0; ht < 4; ++ht) {
            const int h = ht * 16 + c;
            vf[ht] = *(const short8*)(vb + h * 128 + ((wk * 64 + g * 16) ^ ((h & 7) << 4)));
        }

        // ---- QK^T, exp, weight ----
        unsigned short pw[8];
#pragma unroll
        for (int t = 0; t < 2; ++t) {
            f32x4 acc = {};
            acc = MFMA16(qf0, kf[t][0], acc);
            acc = MFMA16(qf1, kf[t][1], acc);
#pragma unroll
            for (int r = 0; r < 4; ++r) {
                const float p = __expf(acc[r] * 0.125f) * bcur[t * 4 + r];
                dsum[r] += p;
                pw[t * 4 + r] = f2bf(p);
            }
        }

        // ---- P bounce (wave-local, stride 36 ushorts) ----
#pragma unroll
        for (int t = 0; t < 2; ++t)
#pragma unroll
            for (int r = 0; r < 4; ++r)
                Pw[(g * 4 + r) * 36 + t * 16 + c] = pw[t * 4 + r];
        __builtin_amdgcn_wave_barrier();
        const short8 pa = *(const short8*)(Pw + c * 36 + g * 8);

        // ---- PV ----
#pragma unroll
        for (int ht = 0; ht < 4; ++ht)
            vals[ht] = MFMA16(pa, vf[ht], vals[ht]);

        if (it + 1 < NIT3) {
            if (pre) asm volatile("s_waitcnt vmcnt(6)" ::: "memory");
            else     asm volatile("s_waitcnt vmcnt(0)" ::: "memory");
            __builtin_amdgcn_s_barrier();
        }
        // rotate buffers
        char* t0 = b0; b0 = b1; b1 = b2; b2 = t0;
    }

    // ---- denominator across the 16 c-lanes ----
#pragma unroll
    for (int r = 0; r < 4; ++r) {
        float v = dsum[r];
        v += __shfl_xor(v, 1);
        v += __shfl_xor(v, 2);
        v += __shfl_xor(v, 4);
        v += __shfl_xor(v, 8);
        dsum[r] = v;
    }

    // ---- cross-wk combine; rv (16.6KB) aliases the first stage buffer region ----
    float* rv = (float*)smem;  // [2 wk][32 q][65]
#pragma unroll
    for (int ht = 0; ht < 4; ++ht)
#pragma unroll
        for (int r = 0; r < 4; ++r)
            rv[(wk * 32 + wq * 16 + g * 4 + r) * 65 + ht * 16 + c] = vals[ht][r];
    if (c == 0) {
#pragma unroll
        for (int r = 0; r < 4; ++r)
            rv[(wk * 32 + wq * 16 + g * 4 + r) * 65 + 64] = dsum[r];
    }
    __syncthreads();

    const int h = tid & 63;
    for (int qq = tid >> 6; qq < QB2; qq += 4) {
        const float v = rv[qq * 65 + h] + rv[(32 + qq) * 65 + h];
        pv[((size_t)bid * QB2 + qq) * H + h] = v;
        if (h == 0)
            pd[(size_t)bid * QB2 + qq] = rv[qq * 65 + 64] + rv[(32 + qq) * 65 + 64];
    }
}

// -------- kernel 4: combine key-split partials, divide, ELU --------
__global__ __launch_bounds__(256) void reduce_kernel(const float* __restrict__ pv,
                                                     const float* __restrict__ pd,
                                                     float* __restrict__ out) {
    const int i = blockIdx.x * 256 + threadIdx.x;  // N*H
    const int q = i >> 6, h = i & 63;
    const int qc = q >> 5, qi = q & 31;
    float v = 0.f, d = 0.f;
#pragma unroll
    for (int ks = 0; ks < KSPLIT; ++ks) {
        const size_t row = (size_t)(qc * KSPLIT + ks) * QB2 + qi;
        v += pv[row * H + h];
        d += pd[row];
    }
    const float x = v / (d + 1e-19f);
    out[i] = x > 0.f ? x : expm1f(x);
}

extern "C" void kernel_launch(void* const* d_in, const int* in_sizes, int n_in,
                              void* d_out, int out_size, void* d_ws, size_t ws_size,
                              hipStream_t stream) {
    const float* seq  = (const float*)d_in[0];
    const float* bias = (const float*)d_in[1];
    const float* W1   = (const float*)d_in[2];
    const float* W2   = (const float*)d_in[3];
    // d_in[4] = bias_zero (zeros) -- folded out
    float* out = (float*)d_out;

    unsigned short* Qb  = (unsigned short*)d_ws;   // 1 MB (also V)
    unsigned short* Kb  = Qb + (size_t)N * H;      // 1 MB
    unsigned short* QT  = Kb + (size_t)N * H;      // 1 MB (V^T)
    unsigned short* W1T = QT + (size_t)N * H;      // 16 KB
    unsigned short* W2T = W1T + (size_t)H * FIN;   // 16 KB
    float* pv = (float*)(W2T + (size_t)H * FIN);   // 1024*32*64 f32 = 8 MB
    float* pd = pv + (size_t)(N / QB2) * KSPLIT * QB2 * H;  // 128 KB

    wprep_kernel<<<32, 256, 0, stream>>>(W1, W2, W1T, W2T);
    proj_kernel<<<N / 32, 256, 0, stream>>>(seq, W1T, W2T, Qb, Kb);
    tr_kernel<<<N / 64, 256, 0, stream>>>(Qb, QT);
    flash_kernel<<<(N / QB2) * KSPLIT, 256, 0, stream>>>(Qb, Kb, QT, bias, pv, pd);
    reduce_kernel<<<(N * H) / 256, 256, 0, stream>>>(pv, pd, out);
}

// Round 6
// 97.548 us; speedup vs baseline: 3.3589x; 1.0209x over previous
//
#include <hip/hip_runtime.h>
#include <hip/hip_bf16.h>
#include <stdint.h>

#define N 8192
#define FIN 128
#define H 64
#define QB2 32                   // query rows per block
#define MB2 64                   // keys per iteration
#define KSPLIT 4
#define KLEN (N / KSPLIT)        // 2048 keys per block
#define NIT3 (KLEN / MB2)        // 32 iterations
#define STAGE_BYTES 16384        // K 8KB + V 8KB

typedef __attribute__((ext_vector_type(8))) short short8;
typedef __attribute__((ext_vector_type(4))) float f32x4;

#define MFMA16(a, b, c) __builtin_amdgcn_mfma_f32_16x16x32_bf16(a, b, c, 0, 0, 0)

typedef __attribute__((address_space(1))) const void* gas_p;
typedef __attribute__((address_space(3))) void* las_p;

static __device__ __forceinline__ void load_lds16(const void* g, void* l) {
    // dest is wave-uniform base; HW writes lane i at base + i*16.
    __builtin_amdgcn_global_load_lds((gas_p)g, (las_p)l, 16, 0, 0);
}

static __device__ __forceinline__ unsigned short f2bf(float f) {
    unsigned int u = __float_as_uint(f);
    unsigned int r = (u + 0x7FFFu + ((u >> 16) & 1u)) >> 16;
    return (unsigned short)r;
}

// pack two f32 -> two bf16 in one u32 (lo = a, hi = b)
static __device__ __forceinline__ unsigned int cvt_pk_bf16(float a, float b) {
    unsigned int r;
    asm("v_cvt_pk_bf16_f32 %0, %1, %2" : "=v"(r) : "v"(a), "v"(b));
    return r;
}

// -------- kernel 0: W -> W^T bf16; W2 pre-scaled by log2(e)/8 (K-side only) --------
__global__ __launch_bounds__(256) void wprep_kernel(const float* __restrict__ W1,
                                                    const float* __restrict__ W2,
                                                    unsigned short* __restrict__ W1T,
                                                    unsigned short* __restrict__ W2T) {
    const int i = blockIdx.x * 256 + threadIdx.x;
    const int h = i >> 7, f = i & 127;
    W1T[i] = f2bf(W1[f * H + h]);
    W2T[i] = f2bf(W2[f * H + h] * 0.18033688011112042f);  // log2(e)/8
}

// -------- kernel 1: MFMA projection seq @ W -> Q(=V), K in bf16 --------
// 256 blocks x 32 rows. Waves 0-1: W1 -> Qb; waves 2-3: W2 -> Kb.
__global__ __launch_bounds__(256) void proj_kernel(const float* __restrict__ seq,
                                                   const unsigned short* __restrict__ W1T,
                                                   const unsigned short* __restrict__ W2T,
                                                   unsigned short* __restrict__ Qb,
                                                   unsigned short* __restrict__ Kb) {
    const int tid = threadIdx.x;
    const int w = tid >> 6, lane = tid & 63;
    const int g = lane >> 4, c = lane & 15;
    const int wq = w & 1, ww = w >> 1;
    const int r0 = blockIdx.x * 32 + wq * 16;
    const unsigned short* WT = ww ? W2T : W1T;
    unsigned short* Ob = ww ? Kb : Qb;

    short8 af[4];
#pragma unroll
    for (int kc = 0; kc < 4; ++kc) {
        const float* sp = seq + (size_t)(r0 + c) * FIN + kc * 32 + g * 8;
        const f32x4 s0 = *(const f32x4*)sp;
        const f32x4 s1 = *(const f32x4*)(sp + 4);
        short8 v;
#pragma unroll
        for (int j = 0; j < 4; ++j) {
            v[j] = (short)f2bf(s0[j]);
            v[4 + j] = (short)f2bf(s1[j]);
        }
        af[kc] = v;
    }

    f32x4 oa[4] = {};
#pragma unroll
    for (int kc = 0; kc < 4; ++kc) {
#pragma unroll
        for (int ht = 0; ht < 4; ++ht) {
            const short8 wf = *(const short8*)(WT + (size_t)(ht * 16 + c) * FIN + kc * 32 + g * 8);
            oa[ht] = MFMA16(af[kc], wf, oa[ht]);
        }
    }
#pragma unroll
    for (int ht = 0; ht < 4; ++ht)
#pragma unroll
        for (int r = 0; r < 4; ++r) {
            const int row = r0 + g * 4 + r;
            Ob[(size_t)row * H + ht * 16 + c] = f2bf(oa[ht][r]);
        }
}

// -------- kernel 2: transpose Qb -> QT[64][8192] (= V^T) --------
__global__ __launch_bounds__(256) void tr_kernel(const unsigned short* __restrict__ Qb,
                                                 unsigned short* __restrict__ QT) {
    __shared__ unsigned short t[64][65];
    const int m0 = blockIdx.x * 64;
    const int tid = threadIdx.x;
    for (int i = tid; i < 64 * 64; i += 256) {
        const int m = i >> 6, h = i & 63;
        t[h][m] = Qb[(size_t)(m0 + m) * H + h];
    }
    __syncthreads();
    for (int i = tid; i < 64 * 64; i += 256) {
        const int h = i >> 6, m = i & 63;
        QT[(size_t)h * N + m0 + m] = t[h][m];
    }
}

// -------- kernel 3: flash partials — K/V LDS double-buffer, bias in registers --------
// 1024 blocks (256 q-chunks x KSPLIT) -> 4 blocks/CU (37.4KB LDS), 16 waves/CU.
// Per iter: stage(it+1) [4 loads/wave] + bias(it+1) reg prefetch [8 dwords/lane],
// compute tile it, __syncthreads.
__global__ __launch_bounds__(256, 4) void flash_kernel(const unsigned short* __restrict__ Qb,
                                                       const unsigned short* __restrict__ Kb,
                                                       const unsigned short* __restrict__ QT,
                                                       const float* __restrict__ bias,
                                                       float* __restrict__ pv,
                                                       float* __restrict__ pd) {
    __shared__ char smem[2 * STAGE_BYTES + 4 * 16 * 36 * 2];  // 37376 B

    const int tid = threadIdx.x;
    const int w = tid >> 6, lane = tid & 63;
    const int g = lane >> 4, c = lane & 15;
    const int wq = w >> 1, wk = w & 1;
    const int bid = blockIdx.x;
    const int q0 = (bid >> 2) * QB2;
    const int mbase = (bid & 3) * KLEN;

    unsigned short* Pw = (unsigned short*)(smem + 2 * STAGE_BYTES) + w * (16 * 36);

    // Q A-fragments for this wave's 16 rows (row=c, k=g*8+j)
    short8 qf0, qf1;
    {
        const unsigned short* qrow = Qb + (size_t)(q0 + wq * 16 + c) * H + g * 8;
        qf0 = *(const short8*)(qrow);
        qf1 = *(const short8*)(qrow + 32);
    }
    // all-ones bf16 B-fragment for the denominator MFMA
    const short8 ones = {0x3F80, 0x3F80, 0x3F80, 0x3F80, 0x3F80, 0x3F80, 0x3F80, 0x3F80};

    f32x4 vals[4] = {};   // PV accum; D row=q(g*4+r), col=h(ht*16+c)
    f32x4 vden = {};      // denominator accum (replicated over cols)

    // stage one 64-key tile (K + V^T); exactly 4 global_load_lds per wave
    auto stage = [&](char* sbase, int m0) {
#pragma unroll
        for (int s2 = 0; s2 < 2; ++s2) {
            const int s = w * 2 + s2;          // 0..7
            {   // K: [64 m][64 h] bf16, swz byte ^= (m&7)<<4
                const int m = s * 8 + (lane >> 3);
                const int srcb = ((lane & 7) * 16) ^ ((m & 7) << 4);
                load_lds16((const char*)Kb + (size_t)(mbase + m0 + m) * 128 + srcb,
                           sbase + s * 1024);
            }
            {   // V^T: [64 h][64 m] bf16, swz byte ^= (h&7)<<4
                const int h = s * 8 + (lane >> 3);
                const int srcb = ((lane & 7) * 16) ^ ((h & 7) << 4);
                load_lds16((const char*)QT + (size_t)h * (N * 2) + (size_t)(mbase + m0) * 2 + srcb,
                           sbase + 8192 + s * 1024);
            }
        }
    };

    char* b0 = smem;
    char* b1 = smem + STAGE_BYTES;

    // per-lane bias base: row = q0+wq*16+g*4 (+r), col = mbase+wk*32+c (+it*64+t*16)
    const float* bb = bias + (size_t)(q0 + wq * 16 + g * 4) * N + mbase + wk * 32 + c;

    stage(b0, 0);
    float bcur[8];
#pragma unroll
    for (int t = 0; t < 2; ++t)
#pragma unroll
        for (int r = 0; r < 4; ++r)
            bcur[t * 4 + r] = bb[(size_t)r * N + t * 16];
    __syncthreads();

    for (int it = 0; it < NIT3; ++it) {
        float bnext[8];
        if (it + 1 < NIT3) {
            stage(b1, (it + 1) * MB2);
#pragma unroll
            for (int t = 0; t < 2; ++t)
#pragma unroll
                for (int r = 0; r < 4; ++r)
                    bnext[t * 4 + r] = bb[(size_t)r * N + (it + 1) * 64 + t * 16];
        }

        const char* kb = b0;
        const char* vb = b0 + 8192;

        // K fragments: B[k=h][col=key], key = wk*32 + t*16 + c
        short8 kf[2][2];
#pragma unroll
        for (int t = 0; t < 2; ++t) {
            const int m = wk * 32 + t * 16 + c;
            const char* kr = kb + m * 128;
            const int sw = (m & 7) << 4;
            kf[t][0] = *(const short8*)(kr + ((g * 16) ^ sw));
            kf[t][1] = *(const short8*)(kr + ((64 + g * 16) ^ sw));
        }
        // V^T fragments: B[k=key_local][col=h], h = ht*16 + c
        short8 vf[4];
#pragma unroll
        for (int ht = 0; ht < 4; ++ht) {
            const int h = ht * 16 + c;
            vf[ht] = *(const short8*)(vb + h * 128 + ((wk * 64 + g * 16) ^ ((h & 7) << 4)));
        }

        // ---- QK^T (K pre-scaled by log2e/8), exp2, bias weight ----
        f32x4 acc0 = {}, acc1 = {};
        acc0 = MFMA16(qf0, kf[0][0], acc0);
        acc0 = MFMA16(qf1, kf[0][1], acc0);
        acc1 = MFMA16(qf0, kf[1][0], acc1);
        acc1 = MFMA16(qf1, kf[1][1], acc1);

#pragma unroll
        for (int r = 0; r < 4; ++r) {
            const float p0 = exp2f(acc0[r]) * bcur[r];
            const float p1 = exp2f(acc1[r]) * bcur[4 + r];
            const unsigned int pk = cvt_pk_bf16(p0, p1);
            Pw[(g * 4 + r) * 36 + c] = (unsigned short)(pk & 0xFFFFu);
            Pw[(g * 4 + r) * 36 + 16 + c] = (unsigned short)(pk >> 16);
        }
        __builtin_amdgcn_wave_barrier();
        const short8 pa = *(const short8*)(Pw + c * 36 + g * 8);

        // ---- PV + denominator ----
#pragma unroll
        for (int ht = 0; ht < 4; ++ht)
            vals[ht] = MFMA16(pa, vf[ht], vals[ht]);
        vden = MFMA16(pa, ones, vden);

        __syncthreads();  // stage(it+1) drained; buffers swap safely
        { char* t0 = b0; b0 = b1; b1 = t0; }
        if (it + 1 < NIT3) {
#pragma unroll
            for (int i = 0; i < 8; ++i) bcur[i] = bnext[i];
        }
    }

    // ---- cross-wk combine; rv (16.6KB) aliases the stage buffers (loop done) ----
    float* rv = (float*)smem;  // [2 wk][32 q][65]
#pragma unroll
    for (int ht = 0; ht < 4; ++ht)
#pragma unroll
        for (int r = 0; r < 4; ++r)
            rv[(wk * 32 + wq * 16 + g * 4 + r) * 65 + ht * 16 + c] = vals[ht][r];
    if (c == 0) {
#pragma unroll
        for (int r = 0; r < 4; ++r)
            rv[(wk * 32 + wq * 16 + g * 4 + r) * 65 + 64] = vden[r];
    }
    __syncthreads();

    const int h = tid & 63;
    for (int qq = tid >> 6; qq < QB2; qq += 4) {
        const float v = rv[qq * 65 + h] + rv[(32 + qq) * 65 + h];
        pv[((size_t)bid * QB2 + qq) * H + h] = v;
        if (h == 0)
            pd[(size_t)bid * QB2 + qq] = rv[qq * 65 + 64] + rv[(32 + qq) * 65 + 64];
    }
}

// -------- kernel 4: combine key-split partials, divide, ELU --------
__global__ __launch_bounds__(256) void reduce_kernel(const float* __restrict__ pv,
                                                     const float* __restrict__ pd,
                                                     float* __restrict__ out) {
    const int i = blockIdx.x * 256 + threadIdx.x;  // N*H
    const int q = i >> 6, h = i & 63;
    const int qc = q >> 5, qi = q & 31;
    float v = 0.f, d = 0.f;
#pragma unroll
    for (int ks = 0; ks < KSPLIT; ++ks) {
        const size_t row = (size_t)(qc * KSPLIT + ks) * QB2 + qi;
        v += pv[row * H + h];
        d += pd[row];
    }
    const float x = v / (d + 1e-19f);
    out[i] = x > 0.f ? x : expm1f(x);
}

extern "C" void kernel_launch(void* const* d_in, const int* in_sizes, int n_in,
                              void* d_out, int out_size, void* d_ws, size_t ws_size,
                              hipStream_t stream) {
    const float* seq  = (const float*)d_in[0];
    const float* bias = (const float*)d_in[1];
    const float* W1   = (const float*)d_in[2];
    const float* W2   = (const float*)d_in[3];
    // d_in[4] = bias_zero (zeros) -- folded out
    float* out = (float*)d_out;

    unsigned short* Qb  = (unsigned short*)d_ws;   // 1 MB (also V)
    unsigned short* Kb  = Qb + (size_t)N * H;      // 1 MB
    unsigned short* QT  = Kb + (size_t)N * H;      // 1 MB (V^T)
    unsigned short* W1T = QT + (size_t)N * H;      // 16 KB
    unsigned short* W2T = W1T + (size_t)H * FIN;   // 16 KB
    float* pv = (float*)(W2T + (size_t)H * FIN);   // 1024*32*64 f32 = 8 MB
    float* pd = pv + (size_t)(N / QB2) * KSPLIT * QB2 * H;  // 128 KB

    wprep_kernel<<<32, 256, 0, stream>>>(W1, W2, W1T, W2T);
    proj_kernel<<<N / 32, 256, 0, stream>>>(seq, W1T, W2T, Qb, Kb);
    tr_kernel<<<N / 64, 256, 0, stream>>>(Qb, QT);
    flash_kernel<<<(N / QB2) * KSPLIT, 256, 0, stream>>>(Qb, Kb, QT, bias, pv, pd);
    reduce_kernel<<<(N * H) / 256, 256, 0, stream>>>(pv, pd, out);
}